// Round 2
// baseline (282.680 us; speedup 1.0000x reference)
//
#include <hip/hip_runtime.h>
#include <hip/hip_fp16.h>

// FrameConsistencyLoss: mean over (N,64) of (proj_a - proj_b)^2,
// proj_x[i] = x[i] @ W[ids_x[i]] + b[ids_x[i]]; N=2e6, REL_DIM=14, CAN_DIM=64, 4 experts.
//
// R6: coalesced global loads + LDS row re-gather.
//  R5 post-mortem: doubling occupancy (8->16 blk/CU) left dur EXACTLY flat
//  (108us) => serialized on a per-CU shared resource, not wave latency.
//  Theory: the 56B-stride 16B/lane gathers made every VMEM instr touch ~56
//  scattered cache lines (~480 TCP cy/chunk/CU) and re-touched each line 4x
//  through a thrashing 32KB L1. Fix: lane-LINEAR loads of the dense 3584B
//  chunk regions (3x dwordx4 + 1x dwordx2 per array; 4-lane line merges),
//  stage raw f32 to LDS (conflict-free linear b128 writes), per-lane row
//  re-gather from LDS (stride-56B b64 reads, conflict-free in 16-lane
//  groups), then the existing pack+scatter into the f16 MFMA buffer.
//  The f32 staging (7168B) OVERLAYS the packed buffer (9216B): single-wave
//  blocks + in-order per-wave DS FIFO (same invariant as R5's single buffer)
//  make read-before-clobber safe with zero barriers. LDS stays 9216B =>
//  16 blocks/CU (4 waves/SIMD) preserved.
//
//   Row r: diff_emb[k]: window 14*ea..+13 gets +a (f16), window 14*eb..+13 gets -b,
//   one-hot +1 at k=56+ea, -1 at k=56+eb (bias rows of W~); if ea==eb the windows
//   merge to (a-b) and the one-hots cancel. D = diff_emb @ W~ via 2 chained
//   mfma_f32_16x16x32_f16 per (row-tile, col-tile); loss += sum(D^2).

#define N_ROWS   2000000
#define N_CHUNKS (N_ROWS / 64)   // 31250 chunks of 64 rows
#define NBLK     4096            // 16 blocks/CU x 256 CUs, persistent
#define LDSW     36              // dwords per packed LDS row (64 ushorts + 8 pad)

typedef _Float16     h8 __attribute__((ext_vector_type(8)));
typedef float        f4 __attribute__((ext_vector_type(4)));
typedef unsigned int u4 __attribute__((ext_vector_type(4)));
typedef unsigned int u2 __attribute__((ext_vector_type(2)));

__device__ __forceinline__ unsigned int pkrtz(float a, float b) {
    return __builtin_bit_cast(unsigned int, __builtin_amdgcn_cvt_pkrtz(a, b));
}

struct RawRegs {                 // lane-linear pieces of the chunk's raw data
    u4 a4[3]; u2 a2;             // A: bytes [lane*16 + j*1024), tail [3072 + lane*8)
    u4 b4[3]; u2 b2;
    int ea, eb;
};

__device__ __forceinline__ RawRegs load_chunk(int c, int lane,
        const float* __restrict__ A, const float* __restrict__ B,
        const int* __restrict__ IDA, const int* __restrict__ IDB) {
    RawRegs r;
    const char* pa = (const char*)A + (size_t)c * 3584;
    const char* pb = (const char*)B + (size_t)c * 3584;
#pragma unroll
    for (int j = 0; j < 3; ++j) {
        r.a4[j] = *(const u4*)(pa + j * 1024 + lane * 16);
        r.b4[j] = *(const u4*)(pb + j * 1024 + lane * 16);
    }
    r.a2 = *(const u2*)(pa + 3072 + lane * 8);
    r.b2 = *(const u2*)(pb + 3072 + lane * 8);
    r.ea = IDA[c * 64 + lane];
    r.eb = IDB[c * 64 + lane];
    return r;
}

// Raw f32 staging: A dwords [0,896), B dwords [896,1792) of the shared block.
__device__ __forceinline__ void stage_write(unsigned int* __restrict__ s, int lane,
                                            const RawRegs& r) {
#pragma unroll
    for (int j = 0; j < 3; ++j) {
        *(u4*)(s +       j * 256 + lane * 4) = r.a4[j];   // conflict-free linear b128
        *(u4*)(s + 896 + j * 256 + lane * 4) = r.b4[j];
    }
    *(u2*)(s +       768 + lane * 2) = r.a2;
    *(u2*)(s + 896 + 768 + lane * 2) = r.b2;
}

// Row re-gather (stride-56B b64 reads, conflict-free) + pack + scatter into the
// packed f16 row at dword lane*LDSW (overlays the staging region; safe via the
// in-order per-wave DS FIFO: all reads here are issued before any store below).
__device__ __forceinline__ void pack_scatter(unsigned int* __restrict__ s, int lane,
                                             int ea, int eb) {
    const float* sa = (const float*)s + 14 * lane;          // 8B-aligned
    const float* sb = (const float*)s + 896 + 14 * lane;
    unsigned int pa[7], pb[7];
    const bool same = (ea == eb);
#pragma unroll
    for (int t = 0; t < 7; ++t) {
        float2 av = *(const float2*)(sa + 2 * t);
        float2 bv = *(const float2*)(sb + 2 * t);
        float sx = same ? (av.x - bv.x) : av.x;
        float sy = same ? (av.y - bv.y) : av.y;
        pa[t] = pkrtz(sx, sy);
        pb[t] = pkrtz(-bv.x, -bv.y);
    }
    unsigned int* row32 = s + lane * LDSW;
    const u4 z = {0u, 0u, 0u, 0u};
#pragma unroll
    for (int t = 0; t < 8; ++t) ((u4*)row32)[t] = z;        // zero k=0..63
#pragma unroll
    for (int t = 0; t < 7; ++t) row32[7 * ea + t] = pa[t];  // +a (or a-b if same)
    if (!same) {
#pragma unroll
        for (int t = 0; t < 7; ++t) row32[7 * eb + t] = pb[t];
        const unsigned wa = 0x3C00u << ((ea & 1) * 16);     // +1.0h at k=56+ea
        const unsigned wb = 0xBC00u << ((eb & 1) * 16);     // -1.0h at k=56+eb
        const int ja = 28 + (ea >> 1), jb = 28 + (eb >> 1);
        if (ja == jb) row32[ja] = wa | wb;
        else { row32[ja] = wa; row32[jb] = wb; }
    }
}

__device__ __forceinline__ void compute_chunk(const unsigned int* __restrict__ sbuf,
                                              int sub, int quad, const h8* wf,
                                              float* ls) {
#pragma unroll
    for (int t = 0; t < 4; ++t) {
        const unsigned int* fr = sbuf + (t * 16 + sub) * LDSW + quad * 4;
        u4 lo = *(const u4*)fr;          // k = quad*8 .. +7
        u4 hi = *(const u4*)(fr + 16);   // k = 32+quad*8 .. +7
        const h8 e0 = __builtin_bit_cast(h8, lo);
        const h8 e1 = __builtin_bit_cast(h8, hi);
#pragma unroll
        for (int ct = 0; ct < 4; ++ct) {
            const f4 z = {0.0f, 0.0f, 0.0f, 0.0f};
            f4 acc = __builtin_amdgcn_mfma_f32_16x16x32_f16(e0, wf[ct * 2 + 0], z, 0, 0, 0);
            acc     = __builtin_amdgcn_mfma_f32_16x16x32_f16(e1, wf[ct * 2 + 1], acc, 0, 0, 0);
#pragma unroll
            for (int rr = 0; rr < 4; ++rr)
                ls[rr] = fmaf(acc[rr], acc[rr], ls[rr]);
        }
    }
}

__global__ void __launch_bounds__(64, 4)
frame_loss(const float* __restrict__ A, const float* __restrict__ B,
           const int* __restrict__ IDA, const int* __restrict__ IDB,
           const float* __restrict__ W, const float* __restrict__ BIAS,
           float* __restrict__ ws)
{
    // One 9216B block: f32 staging (dwords 0..1791) overlays packed rows
    // (row r at dword 36r, 64 rows -> 2304 dwords).
    __shared__ alignas(16) unsigned int s0[64 * LDSW];

    const int lane = threadIdx.x;        // block = 1 wave
    const int sub  = lane & 15;
    const int quad = lane >> 4;

    // ---- W~ B-fragments in registers (once): frag f=ct*2+s, elem j:
    // k = s*32 + quad*8 + j, col c = ct*16 + sub. W~[k][c] = W (k<56), bias (56..59), 0.
    h8 wf[8];
#pragma unroll
    for (int ct = 0; ct < 4; ++ct)
#pragma unroll
        for (int s = 0; s < 2; ++s) {
            h8 f;
            const int c = ct * 16 + sub;
#pragma unroll
            for (int j = 0; j < 8; ++j) {
                const int k = s * 32 + quad * 8 + j;
                float v = 0.0f;
                if (k < 56)       v = W[k * 64 + c];           // (4,14,64) flat == W~ rows 0..55
                else if (k < 60)  v = BIAS[(k - 56) * 64 + c]; // bias rows 56..59
                f[j] = (_Float16)v;
            }
            wf[ct * 2 + s] = f;
        }

    float ls[4] = {0.0f, 0.0f, 0.0f, 0.0f};
    const int stride = gridDim.x;

    int c = blockIdx.x;
    RawRegs rr = load_chunk(c, lane, A, B, IDA, IDB);
    stage_write(s0, lane, rr);
    pack_scatter(s0, lane, rr.ea, rr.eb);

    while (true) {
        int n = c + stride;
        bool more = (n < N_CHUNKS);
        if (more) rr = load_chunk(n, lane, A, B, IDA, IDB);   // issue early; hides under MFMA
        compute_chunk(s0, sub, quad, wf, ls);                 // frag-reads P(c) issued first
        if (!more) break;
        stage_write(s0, lane, rr);        // clobbers P-rows<50 AFTER their frag-reads (FIFO)
        pack_scatter(s0, lane, rr.ea, rr.eb);  // row-reads S(n) before scatter clobbers S
        c = n;
    }

    float lsum = ls[0] + ls[1] + ls[2] + ls[3];
#pragma unroll
    for (int off = 32; off > 0; off >>= 1)
        lsum += __shfl_down(lsum, off, 64);
    if (lane == 0)
        ws[blockIdx.x] = lsum;     // no atomic: per-block partial
}

__global__ void __launch_bounds__(256)
reduce_partials(const float* __restrict__ ws, float* __restrict__ out, int nblk)
{
    const int tid = threadIdx.x;
    float s = 0.0f;
    for (int i = tid; i < nblk; i += 256) s += ws[i];
#pragma unroll
    for (int off = 32; off > 0; off >>= 1)
        s += __shfl_down(s, off, 64);
    __shared__ float tmp[4];
    if ((tid & 63) == 0) tmp[tid >> 6] = s;
    __syncthreads();
    if (tid == 0)
        out[0] = (tmp[0] + tmp[1] + tmp[2] + tmp[3]) * (1.0f / 128000000.0f); // 1/(N*64)
}

extern "C" void kernel_launch(void* const* d_in, const int* in_sizes, int n_in,
                              void* d_out, int out_size, void* d_ws, size_t ws_size,
                              hipStream_t stream) {
    const float* A    = (const float*)d_in[0];
    const float* B    = (const float*)d_in[1];
    const int*   IDA  = (const int*)d_in[2];
    const int*   IDB  = (const int*)d_in[3];
    const float* W    = (const float*)d_in[4];
    const float* BIAS = (const float*)d_in[5];
    float* ws  = (float*)d_ws;     // needs NBLK*4 = 16 KB of scratch
    float* out = (float*)d_out;

    // fall back to a 2048-block grid if the workspace is unexpectedly small
    const int nblk = (ws_size >= (size_t)NBLK * sizeof(float)) ? NBLK : 2048;

    frame_loss<<<dim3(nblk), dim3(64), 0, stream>>>(A, B, IDA, IDB, W, BIAS, ws);
    reduce_partials<<<dim3(1), dim3(256), 0, stream>>>(ws, out, nblk);
}